// Round 7
// baseline (587.300 us; speedup 1.0000x reference)
//
#include <hip/hip_runtime.h>
#include <hip/hip_fp16.h>
#include <cstdio>

constexpr int TS = 16;        // halves per row (32B rows; 10 used)
constexpr int NPB = 512;      // nodes per bucket (power of 2)
constexpr int BSH = 9;        // log2(NPB)
constexpr int BIN_CHUNK = 8192;  // edges per block in binning passes (LDS reorder buffer)
constexpr int CAP = 18432;    // LDS staging entries in buildcsr (72KB)

__device__ __forceinline__ float2 h2f(int bits) {
  __half2 h;
  *reinterpret_cast<int*>(&h) = bits;
  return __half22float2(h);
}
__device__ __forceinline__ int f2h(float a, float b) {
  __half2 h = __floats2half2_rn(a, b);
  return *reinterpret_cast<int*>(&h);
}

// ---------------- bucketed CSR build (zero per-edge global atomics, coalesced shuffle) -------

__global__ __launch_bounds__(256) void k_histpb(const int* __restrict__ dst, int* __restrict__ hist,
                                                int E, int nblocks, int nbuck) {
  __shared__ int h[512];
  int t = threadIdx.x;
  h[t] = 0;
  h[t + 256] = 0;
  __syncthreads();
  int e0 = blockIdx.x * BIN_CHUNK + t;
  int eend = min(E, (blockIdx.x + 1) * BIN_CHUNK);
  for (int e = e0; e < eend; e += 256) atomicAdd(&h[dst[e] >> BSH], 1);
  __syncthreads();
  for (int b = t; b < nbuck; b += 256) hist[(size_t)b * nblocks + blockIdx.x] = h[b];
}

__global__ __launch_bounds__(256) void k_scanA(const int* __restrict__ in, int* __restrict__ out,
                                               int* __restrict__ bsum, int n) {
  int base = blockIdx.x * 2048 + threadIdx.x * 8;
  int v[8];
  int run = 0;
#pragma unroll
  for (int i = 0; i < 8; ++i) { int idx = base + i; v[i] = (idx < n) ? in[idx] : 0; }
#pragma unroll
  for (int i = 0; i < 8; ++i) { int t = v[i]; v[i] = run; run += t; }
  __shared__ int s[256];
  s[threadIdx.x] = run;
  __syncthreads();
  for (int off = 1; off < 256; off <<= 1) {
    int t = (threadIdx.x >= off) ? s[threadIdx.x - off] : 0;
    __syncthreads();
    s[threadIdx.x] += t;
    __syncthreads();
  }
  int toff = s[threadIdx.x] - run;
#pragma unroll
  for (int i = 0; i < 8; ++i) { int idx = base + i; if (idx < n) out[idx] = v[i] + toff; }
  if (threadIdx.x == 255) bsum[blockIdx.x] = s[255];
}

__global__ __launch_bounds__(1024) void k_scanB(int* bsum, int nb) {
  __shared__ int s[1024];
  int t = threadIdx.x;
  int v = (t < nb) ? bsum[t] : 0;
  s[t] = v;
  __syncthreads();
  for (int off = 1; off < 1024; off <<= 1) {
    int tv = (t >= off) ? s[t - off] : 0;
    __syncthreads();
    s[t] += tv;
    __syncthreads();
  }
  if (t < nb) bsum[t] = s[t] - v;  // exclusive
}

__global__ __launch_bounds__(256) void k_scanC(int* __restrict__ out, const int* __restrict__ bsum,
                                               int n, int total) {
  int base = blockIdx.x * 2048 + threadIdx.x * 8;
  int add = bsum[blockIdx.x];
#pragma unroll
  for (int i = 0; i < 8; ++i) { int idx = base + i; if (idx < n) out[idx] += add; }
  if (blockIdx.x == 0 && threadIdx.x == 0) out[n] = total;
}

// Pass 2: reorder chunk in LDS (bucket-major), then write coalesced runs per bucket.
// Packed word: local_dst (9b) << 18 | src (18b).
__global__ __launch_bounds__(256) void k_binR(const int* __restrict__ dst, const int* __restrict__ src,
                                              const int* __restrict__ hist_s, int* __restrict__ bin,
                                              int E, int nblocks, int nbuck) {
  __shared__ int lbuf[BIN_CHUNK];
  __shared__ int lh[512];
  __shared__ int ls[512];
  __shared__ int cur[512];
  __shared__ int gbase[512];
  __shared__ int ps[256];
  int t = threadIdx.x;
  lh[t] = 0;
  lh[t + 256] = 0;
  __syncthreads();
  int e0 = blockIdx.x * BIN_CHUNK + t;
  int eend = min(E, (blockIdx.x + 1) * BIN_CHUNK);
  for (int e = e0; e < eend; e += 256) atomicAdd(&lh[dst[e] >> BSH], 1);
  __syncthreads();
  int v0 = lh[2 * t], v1 = lh[2 * t + 1];
  int pair = v0 + v1;
  ps[t] = pair;
  __syncthreads();
  for (int off = 1; off < 256; off <<= 1) {
    int x = (t >= off) ? ps[t - off] : 0;
    __syncthreads();
    ps[t] += x;
    __syncthreads();
  }
  int pexcl = ps[t] - pair;
  ls[2 * t] = pexcl;
  ls[2 * t + 1] = pexcl + v0;
  cur[2 * t] = pexcl;
  cur[2 * t + 1] = pexcl + v0;
  gbase[2 * t] = (2 * t < nbuck) ? hist_s[(size_t)(2 * t) * nblocks + blockIdx.x] : 0;
  gbase[2 * t + 1] = (2 * t + 1 < nbuck) ? hist_s[(size_t)(2 * t + 1) * nblocks + blockIdx.x] : 0;
  __syncthreads();
  for (int e = e0; e < eend; e += 256) {
    int d = dst[e];
    int b = d >> BSH;
    int slot = atomicAdd(&cur[b], 1);
    lbuf[slot] = ((d & (NPB - 1)) << 18) | src[e];
  }
  __syncthreads();
  int wv = t >> 6, ln = t & 63;
  for (int b = wv; b < nbuck; b += 4) {
    int cnt = lh[b];
    int s0 = ls[b];
    int g0 = gbase[b];
    for (int i = ln; i < cnt; i += 64) bin[g0 + i] = lbuf[s0 + i];
  }
}

// Pass 3: one 512-thread WG per 512-node bucket. Single count pass + single LDS scatter
// + coalesced dump. 76KB LDS -> 2 blocks/CU.
__global__ __launch_bounds__(512) void k_buildcsr(const int* __restrict__ bin, const int* __restrict__ hist_s,
                                                  int* __restrict__ rowptr, int* __restrict__ csr,
                                                  float* __restrict__ dinv, int N, int Etot, int nblocks) {
  __shared__ int cnt[NPB];
  __shared__ int sc[NPB];
  __shared__ int lbuf[CAP];
  int t = threadIdx.x;
  int b = blockIdx.x;
  int node0 = b << BSH;
  int nn = min(NPB, N - node0);
  int ebeg = hist_s[(size_t)b * nblocks];
  int eend = hist_s[(size_t)(b + 1) * nblocks];
  cnt[t] = (t < nn) ? 1 : 0;  // self loop
  __syncthreads();
  for (int p = ebeg + t; p < eend; p += 512) atomicAdd(&cnt[bin[p] >> 18], 1);
  __syncthreads();
  int v = cnt[t];
  sc[t] = v;
  __syncthreads();
  for (int off = 1; off < 512; off <<= 1) {
    int x = (t >= off) ? sc[t - off] : 0;
    __syncthreads();
    sc[t] += x;
    __syncthreads();
  }
  int excl = sc[t] - v;
  int cbase = ebeg + node0;  // preceding buckets are full => node0 self-loops precede
  if (t < nn) {
    rowptr[node0 + t] = cbase + excl;
    dinv[node0 + t] = rsqrtf((float)v);
  }
  int total2 = (eend - ebeg) + nn;
  bool stage = (total2 <= CAP);
  __syncthreads();
  cnt[t] = excl + ((t < nn) ? 1 : 0);  // cursor past self loop
  if (t < nn) {
    if (stage) lbuf[excl] = node0 + t;
    else       csr[cbase + excl] = node0 + t;
  }
  __syncthreads();
  for (int p = ebeg + t; p < eend; p += 512) {
    int w = bin[p];
    int slot = atomicAdd(&cnt[w >> 18], 1);
    if (stage) lbuf[slot] = w & 0x3FFFF;
    else       csr[cbase + slot] = w & 0x3FFFF;
  }
  __syncthreads();
  if (stage)
    for (int i = t; i < total2; i += 512) csr[cbase + i] = lbuf[i];
  if (b == 0 && t == 0) rowptr[N] = Etot + N;
}

// ---------------- x @ W1 -> t (fp16, pre-scaled by dinv_r) ----------------
__global__ __launch_bounds__(256) void k_xw(const float* __restrict__ x, const float* __restrict__ W1,
                                            const float* __restrict__ dinv, __half* __restrict__ t, int n) {
  int tid = blockIdx.x * 256 + threadIdx.x;
  int sub = tid & 15;
  int rowStart = tid >> 4;
  int rowStride = (gridDim.x * 256) >> 4;
  float w[8][10];
#pragma unroll
  for (int jj = 0; jj < 8; ++jj)
#pragma unroll
    for (int k = 0; k < 10; ++k) w[jj][k] = W1[(sub * 8 + jj) * 10 + k];
  for (int row = rowStart; row < n; row += rowStride) {
    const float* xr = x + (size_t)row * 128 + sub * 8;
    float4 a = *(const float4*)xr;
    float4 b = *(const float4*)(xr + 4);
    float xv[8] = {a.x, a.y, a.z, a.w, b.x, b.y, b.z, b.w};
    float acc[10];
#pragma unroll
    for (int k = 0; k < 10; ++k) acc[k] = 0.f;
#pragma unroll
    for (int jj = 0; jj < 8; ++jj)
#pragma unroll
      for (int k = 0; k < 10; ++k) acc[k] = fmaf(xv[jj], w[jj][k], acc[k]);
#pragma unroll
    for (int off = 1; off < 16; off <<= 1)
#pragma unroll
      for (int k = 0; k < 10; ++k) acc[k] += __shfl_xor(acc[k], off);
    if (sub == 0) {
      float d = dinv[row];
      __half* o = t + ((size_t)row << 4);
      int4 wv;
      wv.x = f2h(acc[0] * d, acc[1] * d);
      wv.y = f2h(acc[2] * d, acc[3] * d);
      wv.z = f2h(acc[4] * d, acc[5] * d);
      wv.w = f2h(acc[6] * d, acc[7] * d);
      *(int4*)o = wv;
      *(int*)(o + 8) = f2h(acc[8] * d, acc[9] * d);
    }
  }
}

// ---------------- fused GCN layer (fp16 rows, pre-scaled; no per-edge dinv) ----------------
template <bool USE_W>
__global__ __launch_bounds__(256) void k_agg10(const __half* __restrict__ tin, __half* __restrict__ tout,
                                               const int* __restrict__ csr, const int* __restrict__ rowptr,
                                               const float* __restrict__ dinv_d, const float* __restrict__ dnext,
                                               const float* __restrict__ W, const float* __restrict__ bias,
                                               int n) {
  int tid = blockIdx.x * 256 + threadIdx.x;
  int q = tid >> 4, lane = tid & 15;
  if (q >= n) return;
  int beg = rowptr[q], end = rowptr[q + 1];
  float acc[10];
#pragma unroll
  for (int k = 0; k < 10; ++k) acc[k] = 0.f;
  for (int p = beg + lane; p < end; p += 16) {
    int src = csr[p];
    const __half* r = tin + ((size_t)src << 4);
    int4 a = *(const int4*)r;
    int b = *(const int*)(r + 8);
    float2 f0 = h2f(a.x), f1 = h2f(a.y), f2 = h2f(a.z), f3 = h2f(a.w), f4 = h2f(b);
    acc[0] += f0.x; acc[1] += f0.y; acc[2] += f1.x; acc[3] += f1.y;
    acc[4] += f2.x; acc[5] += f2.y; acc[6] += f3.x; acc[7] += f3.y;
    acc[8] += f4.x; acc[9] += f4.y;
  }
#pragma unroll
  for (int off = 1; off < 16; off <<= 1)
#pragma unroll
    for (int k = 0; k < 10; ++k) acc[k] += __shfl_xor(acc[k], off);
  if (lane < 10) {
    float dd = dinv_d[q];
    float dn = dnext[q];
    float o = bias[lane];
    if (USE_W) {
#pragma unroll
      for (int m = 0; m < 10; ++m) o = fmaf(acc[m] * dd, W[m * 10 + lane], o);
    } else {
      o += acc[lane] * dd;
    }
    o = fmaxf(o, 0.f) * dn;
    tout[((size_t)q << 4) + lane] = __float2half(o);
  }
}

// ---------------- output layer: probs[q] = dd * sum t5'[src] + bo  (t5' pre-scaled) ----------
__global__ __launch_bounds__(256) void k_agg1(const float* __restrict__ t5, float* __restrict__ probs,
                                              const int* __restrict__ csr, const int* __restrict__ rowptr,
                                              const float* __restrict__ dinv, const float* __restrict__ bo,
                                              int n) {
  int tid = blockIdx.x * 256 + threadIdx.x;
  int q = tid >> 4, lane = tid & 15;
  if (q >= n) return;
  int beg = rowptr[q], end = rowptr[q + 1];
  float acc = 0.f;
  for (int p = beg + lane; p < end; p += 16) acc += t5[csr[p]];
#pragma unroll
  for (int off = 1; off < 16; off <<= 1) acc += __shfl_xor(acc, off);
  if (lane == 0) probs[q] = fmaf(dinv[q], acc, bo[0]);
}

// ---------------- t5' = h4' @ Wo (stays pre-scaled), mean un-scales ----------------
__global__ __launch_bounds__(256) void k_t5mean(const __half* __restrict__ h, const float* __restrict__ Wo,
                                                const float* __restrict__ dinv, float* __restrict__ t5,
                                                float* __restrict__ part, int n) {
  int tid = blockIdx.x * 256 + threadIdx.x;
  float wo[10];
#pragma unroll
  for (int k = 0; k < 10; ++k) wo[k] = Wo[k];
  float p[10];
#pragma unroll
  for (int k = 0; k < 10; ++k) p[k] = 0.f;
  for (int rowi = tid; rowi < n; rowi += 128 * 256) {
    const __half* r = h + ((size_t)rowi << 4);
    int4 a = *(const int4*)r;
    int b = *(const int*)(r + 8);
    float2 f0 = h2f(a.x), f1 = h2f(a.y), f2 = h2f(a.z), f3 = h2f(a.w), f4 = h2f(b);
    float hv[10] = {f0.x, f0.y, f1.x, f1.y, f2.x, f2.y, f3.x, f3.y, f4.x, f4.y};
    float s = 0.f;
#pragma unroll
    for (int k = 0; k < 10; ++k) s = fmaf(hv[k], wo[k], s);
    t5[rowi] = s;
    float inv = 1.0f / dinv[rowi];  // un-scale for the mean
#pragma unroll
    for (int k = 0; k < 10; ++k) p[k] = fmaf(hv[k], inv, p[k]);
  }
#pragma unroll
  for (int off = 1; off < 64; off <<= 1)
#pragma unroll
    for (int k = 0; k < 10; ++k) p[k] += __shfl_xor(p[k], off);
  __shared__ float sp[4][10];
  int w = threadIdx.x >> 6, ln = threadIdx.x & 63;
  if (ln == 0) {
#pragma unroll
    for (int k = 0; k < 10; ++k) sp[w][k] = p[k];
  }
  __syncthreads();
  if (threadIdx.x < 10)
    part[blockIdx.x * 10 + threadIdx.x] =
        sp[0][threadIdx.x] + sp[1][threadIdx.x] + sp[2][threadIdx.x] + sp[3][threadIdx.x];
}

__global__ void k_finish(const float* __restrict__ part, const float* __restrict__ Wdn,
                         const float* __restrict__ bdn, const float* __restrict__ Wv,
                         const float* __restrict__ bv, float* __restrict__ out, int n, int nPart) {
  __shared__ float m[10];
  int t = threadIdx.x;
  if (t < 10) {
    float s = 0.f;
    for (int b = 0; b < nPart; ++b) s += part[b * 10 + t];
    m[t] = s / (float)n;
  }
  __syncthreads();
  if (t == 0) {
    float pn = bdn[0], vv = bv[0];
    for (int k = 0; k < 10; ++k) {
      pn = fmaf(m[k], Wdn[k], pn);
      vv = fmaf(m[k], Wv[k], vv);
    }
    out[n] = pn;
    out[n + 1] = vv;
  }
}

extern "C" void kernel_launch(void* const* d_in, const int* in_sizes, int n_in,
                              void* d_out, int out_size, void* d_ws, size_t ws_size,
                              hipStream_t stream) {
  const float* x  = (const float*)d_in[0];
  const int* ei   = (const int*)d_in[1];
  const float* W1 = (const float*)d_in[2];
  const float* b1 = (const float*)d_in[3];
  const float* W2 = (const float*)d_in[4];
  const float* b2 = (const float*)d_in[5];
  const float* Wp = (const float*)d_in[6];
  const float* bp = (const float*)d_in[7];
  const float* W3 = (const float*)d_in[8];
  const float* b3 = (const float*)d_in[9];
  const float* Wo = (const float*)d_in[10];
  const float* bo = (const float*)d_in[11];
  const float* Wdn = (const float*)d_in[12];
  const float* bdn = (const float*)d_in[13];
  const float* Wv = (const float*)d_in[14];
  const float* bv = (const float*)d_in[15];

  int N = in_sizes[0] / 128;
  int E = in_sizes[1] / 2;
  const int* row = ei;
  const int* colv = ei + E;
  float* out = (float*)d_out;
  int nbuck = (N + NPB - 1) >> BSH;            // <= 512
  int bb = (E + BIN_CHUNK - 1) / BIN_CHUNK;
  size_t M = (size_t)nbuck * bb;

  char* ws = (char*)d_ws;
  size_t off = 0;
  auto alloc = [&](size_t b) -> void* {
    void* p = ws + off;
    off += (b + 255) & ~(size_t)255;
    return p;
  };
  int* csr_r = (int*)alloc((size_t)(E + N) * 4);
  int* csr_c = (int*)alloc((size_t)(E + N) * 4);
  int* rp_r = (int*)alloc((size_t)(N + 1) * 4);
  int* rp_c = (int*)alloc((size_t)(N + 1) * 4);
  float* dinv_r = (float*)alloc((size_t)N * 4);
  float* dinv_c = (float*)alloc((size_t)N * 4);
  int* hist = (int*)alloc((M + 1) * 4);
  int* bsum = (int*)alloc(4096);
  // union region: bin (build phase) overlaps t_a/t_b/t5/part (compute phase)
  size_t binB = (size_t)E * 4;
  size_t tB = (size_t)N * TS * 2 * 2 + (size_t)N * 4 + 128 * 10 * 4 + 1024;
  char* region = (char*)alloc(binB > tB ? binB : tB);
  int* bin = (int*)region;
  __half* t_a = (__half*)region;
  __half* t_b = (__half*)(region + (size_t)N * TS * 2);
  float* t5 = (float*)(region + (size_t)N * TS * 2 * 2);
  float* part = (float*)(region + (size_t)N * TS * 2 * 2 + (size_t)N * 4);
  if (off > ws_size) {
    fprintf(stderr, "WS too small: need %zu have %zu\n", off, ws_size);
    return;
  }

  int sb2 = (int)((M + 2047) / 2048);
  int ab = (int)(((size_t)N * 16 + 255) / 256);

  // build row-CSR (dst=row, src=col)
  k_histpb<<<bb, 256, 0, stream>>>(row, hist, E, bb, nbuck);
  k_scanA<<<sb2, 256, 0, stream>>>(hist, hist, bsum, (int)M);
  k_scanB<<<1, 1024, 0, stream>>>(bsum, sb2);
  k_scanC<<<sb2, 256, 0, stream>>>(hist, bsum, (int)M, E);
  k_binR<<<bb, 256, 0, stream>>>(row, colv, hist, bin, E, bb, nbuck);
  k_buildcsr<<<nbuck, 512, 0, stream>>>(bin, hist, rp_r, csr_r, dinv_r, N, E, bb);
  // build col-CSR (dst=col, src=row)
  k_histpb<<<bb, 256, 0, stream>>>(colv, hist, E, bb, nbuck);
  k_scanA<<<sb2, 256, 0, stream>>>(hist, hist, bsum, (int)M);
  k_scanB<<<1, 1024, 0, stream>>>(bsum, sb2);
  k_scanC<<<sb2, 256, 0, stream>>>(hist, bsum, (int)M, E);
  k_binR<<<bb, 256, 0, stream>>>(colv, row, hist, bin, E, bb, nbuck);
  k_buildcsr<<<nbuck, 512, 0, stream>>>(bin, hist, rp_c, csr_c, dinv_c, N, E, bb);

  // network (hidden rows fp16, pre-scaled by the NEXT consumer's dinv)
  k_xw<<<2048, 256, 0, stream>>>(x, W1, dinv_r, t_a, N);
  k_agg10<false><<<ab, 256, 0, stream>>>(t_a, t_b, csr_r, rp_r, dinv_r, dinv_r, nullptr, b1, N);
  k_agg10<true><<<ab, 256, 0, stream>>>(t_b, t_a, csr_r, rp_r, dinv_r, dinv_c, W2, b2, N);
  k_agg10<true><<<ab, 256, 0, stream>>>(t_a, t_b, csr_c, rp_c, dinv_c, dinv_r, Wp, bp, N);
  k_agg10<true><<<ab, 256, 0, stream>>>(t_b, t_a, csr_r, rp_r, dinv_r, dinv_r, W3, b3, N);
  k_t5mean<<<128, 256, 0, stream>>>(t_a, Wo, dinv_r, t5, part, N);
  k_agg1<<<ab, 256, 0, stream>>>(t5, out, csr_r, rp_r, dinv_r, bo, N);
  k_finish<<<1, 64, 0, stream>>>(part, Wdn, bdn, Wv, bv, out, N, 128);
}

// Round 8
// 501.813 us; speedup vs baseline: 1.1704x; 1.1704x over previous
//
#include <hip/hip_runtime.h>
#include <hip/hip_fp16.h>
#include <cstdio>

constexpr int TS = 16;        // halves per row (32B rows; 10 used)
constexpr int NPB = 512;      // nodes per bucket (power of 2)
constexpr int BSH = 9;        // log2(NPB)
constexpr int BIN_CHUNK = 8192;  // edges per block in binning passes (LDS reorder buffer)
constexpr int CAP = 18432;    // LDS staging entries in buildcsr (72KB)

__device__ __forceinline__ float2 h2f(int bits) {
  __half2 h;
  *reinterpret_cast<int*>(&h) = bits;
  return __half22float2(h);
}
__device__ __forceinline__ int f2h(float a, float b) {
  __half2 h = __floats2half2_rn(a, b);
  return *reinterpret_cast<int*>(&h);
}

// ---------------- bucketed CSR build (zero per-edge global atomics, coalesced shuffle) -------

__global__ __launch_bounds__(256) void k_histpb(const int* __restrict__ dst, int* __restrict__ hist,
                                                int E, int nblocks, int nbuck) {
  __shared__ int h[512];
  int t = threadIdx.x;
  h[t] = 0;
  h[t + 256] = 0;
  __syncthreads();
  int e0 = blockIdx.x * BIN_CHUNK + t;
  int eend = min(E, (blockIdx.x + 1) * BIN_CHUNK);
  for (int e = e0; e < eend; e += 256) atomicAdd(&h[dst[e] >> BSH], 1);
  __syncthreads();
  for (int b = t; b < nbuck; b += 256) hist[(size_t)b * nblocks + blockIdx.x] = h[b];
}

__global__ __launch_bounds__(256) void k_scanA(const int* __restrict__ in, int* __restrict__ out,
                                               int* __restrict__ bsum, int n) {
  int base = blockIdx.x * 2048 + threadIdx.x * 8;
  int v[8];
  int run = 0;
#pragma unroll
  for (int i = 0; i < 8; ++i) { int idx = base + i; v[i] = (idx < n) ? in[idx] : 0; }
#pragma unroll
  for (int i = 0; i < 8; ++i) { int t = v[i]; v[i] = run; run += t; }
  __shared__ int s[256];
  s[threadIdx.x] = run;
  __syncthreads();
  for (int off = 1; off < 256; off <<= 1) {
    int t = (threadIdx.x >= off) ? s[threadIdx.x - off] : 0;
    __syncthreads();
    s[threadIdx.x] += t;
    __syncthreads();
  }
  int toff = s[threadIdx.x] - run;
#pragma unroll
  for (int i = 0; i < 8; ++i) { int idx = base + i; if (idx < n) out[idx] = v[i] + toff; }
  if (threadIdx.x == 255) bsum[blockIdx.x] = s[255];
}

__global__ __launch_bounds__(1024) void k_scanB(int* bsum, int nb) {
  __shared__ int s[1024];
  int t = threadIdx.x;
  int v = (t < nb) ? bsum[t] : 0;
  s[t] = v;
  __syncthreads();
  for (int off = 1; off < 1024; off <<= 1) {
    int tv = (t >= off) ? s[t - off] : 0;
    __syncthreads();
    s[t] += tv;
    __syncthreads();
  }
  if (t < nb) bsum[t] = s[t] - v;  // exclusive
}

__global__ __launch_bounds__(256) void k_scanC(int* __restrict__ out, const int* __restrict__ bsum,
                                               int n, int total) {
  int base = blockIdx.x * 2048 + threadIdx.x * 8;
  int add = bsum[blockIdx.x];
#pragma unroll
  for (int i = 0; i < 8; ++i) { int idx = base + i; if (idx < n) out[idx] += add; }
  if (blockIdx.x == 0 && threadIdx.x == 0) out[n] = total;
}

// Pass 2: reorder chunk in LDS (bucket-major), then write out with ALL lanes:
// entry i's bucket found by 9-step binary search over ls[512]; consecutive i ->
// consecutive global addrs (coalesced). Packed word: local_dst(9b)<<18 | src(18b).
__global__ __launch_bounds__(256) void k_binR(const int* __restrict__ dst, const int* __restrict__ src,
                                              const int* __restrict__ hist_s, int* __restrict__ bin,
                                              int E, int nblocks, int nbuck) {
  __shared__ int lbuf[BIN_CHUNK];
  __shared__ int ls[512];     // per-bucket exclusive start
  __shared__ int cur[512];    // scatter cursors
  __shared__ int gbase[512];  // global base per bucket for this chunk
  __shared__ int ps[256];
  int t = threadIdx.x;
  cur[t] = 0;
  cur[t + 256] = 0;
  __syncthreads();
  int blk0 = blockIdx.x * BIN_CHUNK;
  int e0 = blk0 + t;
  int eend = min(E, blk0 + BIN_CHUNK);
  int nent = eend - blk0;
  for (int e = e0; e < eend; e += 256) atomicAdd(&cur[dst[e] >> BSH], 1);
  __syncthreads();
  int v0 = cur[2 * t], v1 = cur[2 * t + 1];
  int pair = v0 + v1;
  ps[t] = pair;
  __syncthreads();
  for (int off = 1; off < 256; off <<= 1) {
    int x = (t >= off) ? ps[t - off] : 0;
    __syncthreads();
    ps[t] += x;
    __syncthreads();
  }
  int pexcl = ps[t] - pair;
  __syncthreads();
  ls[2 * t] = pexcl;
  ls[2 * t + 1] = pexcl + v0;
  cur[2 * t] = pexcl;
  cur[2 * t + 1] = pexcl + v0;
  gbase[2 * t] = (2 * t < nbuck) ? hist_s[(size_t)(2 * t) * nblocks + blockIdx.x] : 0;
  gbase[2 * t + 1] = (2 * t + 1 < nbuck) ? hist_s[(size_t)(2 * t + 1) * nblocks + blockIdx.x] : 0;
  __syncthreads();
  for (int e = e0; e < eend; e += 256) {
    int d = dst[e];
    int b = d >> BSH;
    int slot = atomicAdd(&cur[b], 1);
    lbuf[slot] = ((d & (NPB - 1)) << 18) | src[e];
  }
  __syncthreads();
  // full-lane write-out: bucket of entry i = last b with ls[b] <= i
  for (int i = t; i < nent; i += 256) {
    int w = lbuf[i];
    int lo = 0;
#pragma unroll
    for (int sh = 256; sh > 0; sh >>= 1) {
      int mid = lo + sh;
      if (mid < 512 && ls[mid] <= i) lo = mid;
    }
    bin[gbase[lo] + (i - ls[lo])] = w;
  }
}

// Pass 3: one 512-thread WG per 512-node bucket. Single count pass + single LDS scatter
// + coalesced dump. 76KB LDS -> 2 blocks/CU.
__global__ __launch_bounds__(512) void k_buildcsr(const int* __restrict__ bin, const int* __restrict__ hist_s,
                                                  int* __restrict__ rowptr, int* __restrict__ csr,
                                                  float* __restrict__ dinv, int N, int Etot, int nblocks) {
  __shared__ int cnt[NPB];
  __shared__ int sc[NPB];
  __shared__ int lbuf[CAP];
  int t = threadIdx.x;
  int b = blockIdx.x;
  int node0 = b << BSH;
  int nn = min(NPB, N - node0);
  int ebeg = hist_s[(size_t)b * nblocks];
  int eend = hist_s[(size_t)(b + 1) * nblocks];
  cnt[t] = (t < nn) ? 1 : 0;  // self loop
  __syncthreads();
  for (int p = ebeg + t; p < eend; p += 512) atomicAdd(&cnt[bin[p] >> 18], 1);
  __syncthreads();
  int v = cnt[t];
  sc[t] = v;
  __syncthreads();
  for (int off = 1; off < 512; off <<= 1) {
    int x = (t >= off) ? sc[t - off] : 0;
    __syncthreads();
    sc[t] += x;
    __syncthreads();
  }
  int excl = sc[t] - v;
  int cbase = ebeg + node0;  // preceding buckets are full => node0 self-loops precede
  if (t < nn) {
    rowptr[node0 + t] = cbase + excl;
    dinv[node0 + t] = rsqrtf((float)v);
  }
  int total2 = (eend - ebeg) + nn;
  bool stage = (total2 <= CAP);
  __syncthreads();
  cnt[t] = excl + ((t < nn) ? 1 : 0);  // cursor past self loop
  if (t < nn) {
    if (stage) lbuf[excl] = node0 + t;
    else       csr[cbase + excl] = node0 + t;
  }
  __syncthreads();
  for (int p = ebeg + t; p < eend; p += 512) {
    int w = bin[p];
    int slot = atomicAdd(&cnt[w >> 18], 1);
    if (stage) lbuf[slot] = w & 0x3FFFF;
    else       csr[cbase + slot] = w & 0x3FFFF;
  }
  __syncthreads();
  if (stage)
    for (int i = t; i < total2; i += 512) csr[cbase + i] = lbuf[i];
  if (b == 0 && t == 0) rowptr[N] = Etot + N;
}

// ---------------- x @ W1 -> t (fp16, pre-scaled by dinv_r) ----------------
__global__ __launch_bounds__(256) void k_xw(const float* __restrict__ x, const float* __restrict__ W1,
                                            const float* __restrict__ dinv, __half* __restrict__ t, int n) {
  int tid = blockIdx.x * 256 + threadIdx.x;
  int sub = tid & 15;
  int rowStart = tid >> 4;
  int rowStride = (gridDim.x * 256) >> 4;
  float w[8][10];
#pragma unroll
  for (int jj = 0; jj < 8; ++jj)
#pragma unroll
    for (int k = 0; k < 10; ++k) w[jj][k] = W1[(sub * 8 + jj) * 10 + k];
  for (int row = rowStart; row < n; row += rowStride) {
    const float* xr = x + (size_t)row * 128 + sub * 8;
    float4 a = *(const float4*)xr;
    float4 b = *(const float4*)(xr + 4);
    float xv[8] = {a.x, a.y, a.z, a.w, b.x, b.y, b.z, b.w};
    float acc[10];
#pragma unroll
    for (int k = 0; k < 10; ++k) acc[k] = 0.f;
#pragma unroll
    for (int jj = 0; jj < 8; ++jj)
#pragma unroll
      for (int k = 0; k < 10; ++k) acc[k] = fmaf(xv[jj], w[jj][k], acc[k]);
#pragma unroll
    for (int off = 1; off < 16; off <<= 1)
#pragma unroll
      for (int k = 0; k < 10; ++k) acc[k] += __shfl_xor(acc[k], off);
    if (sub == 0) {
      float d = dinv[row];
      __half* o = t + ((size_t)row << 4);
      int4 wv;
      wv.x = f2h(acc[0] * d, acc[1] * d);
      wv.y = f2h(acc[2] * d, acc[3] * d);
      wv.z = f2h(acc[4] * d, acc[5] * d);
      wv.w = f2h(acc[6] * d, acc[7] * d);
      *(int4*)o = wv;
      *(int*)(o + 8) = f2h(acc[8] * d, acc[9] * d);
    }
  }
}

// ---------------- fused GCN layer (fp16 rows, pre-scaled; no per-edge dinv) ----------------
template <bool USE_W>
__global__ __launch_bounds__(256) void k_agg10(const __half* __restrict__ tin, __half* __restrict__ tout,
                                               const int* __restrict__ csr, const int* __restrict__ rowptr,
                                               const float* __restrict__ dinv_d, const float* __restrict__ dnext,
                                               const float* __restrict__ W, const float* __restrict__ bias,
                                               int n) {
  int tid = blockIdx.x * 256 + threadIdx.x;
  int q = tid >> 4, lane = tid & 15;
  if (q >= n) return;
  int beg = rowptr[q], end = rowptr[q + 1];
  float acc[10];
#pragma unroll
  for (int k = 0; k < 10; ++k) acc[k] = 0.f;
  for (int p = beg + lane; p < end; p += 16) {
    int src = csr[p];
    const __half* r = tin + ((size_t)src << 4);
    int4 a = *(const int4*)r;
    int b = *(const int*)(r + 8);
    float2 f0 = h2f(a.x), f1 = h2f(a.y), f2 = h2f(a.z), f3 = h2f(a.w), f4 = h2f(b);
    acc[0] += f0.x; acc[1] += f0.y; acc[2] += f1.x; acc[3] += f1.y;
    acc[4] += f2.x; acc[5] += f2.y; acc[6] += f3.x; acc[7] += f3.y;
    acc[8] += f4.x; acc[9] += f4.y;
  }
#pragma unroll
  for (int off = 1; off < 16; off <<= 1)
#pragma unroll
    for (int k = 0; k < 10; ++k) acc[k] += __shfl_xor(acc[k], off);
  if (lane < 10) {
    float dd = dinv_d[q];
    float dn = dnext[q];
    float o = bias[lane];
    if (USE_W) {
#pragma unroll
      for (int m = 0; m < 10; ++m) o = fmaf(acc[m] * dd, W[m * 10 + lane], o);
    } else {
      o += acc[lane] * dd;
    }
    o = fmaxf(o, 0.f) * dn;
    tout[((size_t)q << 4) + lane] = __float2half(o);
  }
}

// ---------------- output layer: probs[q] = dd * sum t5'[src] + bo  (t5' pre-scaled) ----------
__global__ __launch_bounds__(256) void k_agg1(const float* __restrict__ t5, float* __restrict__ probs,
                                              const int* __restrict__ csr, const int* __restrict__ rowptr,
                                              const float* __restrict__ dinv, const float* __restrict__ bo,
                                              int n) {
  int tid = blockIdx.x * 256 + threadIdx.x;
  int q = tid >> 4, lane = tid & 15;
  if (q >= n) return;
  int beg = rowptr[q], end = rowptr[q + 1];
  float acc = 0.f;
  for (int p = beg + lane; p < end; p += 16) acc += t5[csr[p]];
#pragma unroll
  for (int off = 1; off < 16; off <<= 1) acc += __shfl_xor(acc, off);
  if (lane == 0) probs[q] = fmaf(dinv[q], acc, bo[0]);
}

// ---------------- t5' = h4' @ Wo (stays pre-scaled), mean un-scales ----------------
__global__ __launch_bounds__(256) void k_t5mean(const __half* __restrict__ h, const float* __restrict__ Wo,
                                                const float* __restrict__ dinv, float* __restrict__ t5,
                                                float* __restrict__ part, int n) {
  int tid = blockIdx.x * 256 + threadIdx.x;
  float wo[10];
#pragma unroll
  for (int k = 0; k < 10; ++k) wo[k] = Wo[k];
  float p[10];
#pragma unroll
  for (int k = 0; k < 10; ++k) p[k] = 0.f;
  for (int rowi = tid; rowi < n; rowi += 128 * 256) {
    const __half* r = h + ((size_t)rowi << 4);
    int4 a = *(const int4*)r;
    int b = *(const int*)(r + 8);
    float2 f0 = h2f(a.x), f1 = h2f(a.y), f2 = h2f(a.z), f3 = h2f(a.w), f4 = h2f(b);
    float hv[10] = {f0.x, f0.y, f1.x, f1.y, f2.x, f2.y, f3.x, f3.y, f4.x, f4.y};
    float s = 0.f;
#pragma unroll
    for (int k = 0; k < 10; ++k) s = fmaf(hv[k], wo[k], s);
    t5[rowi] = s;
    float inv = 1.0f / dinv[rowi];  // un-scale for the mean
#pragma unroll
    for (int k = 0; k < 10; ++k) p[k] = fmaf(hv[k], inv, p[k]);
  }
#pragma unroll
  for (int off = 1; off < 64; off <<= 1)
#pragma unroll
    for (int k = 0; k < 10; ++k) p[k] += __shfl_xor(p[k], off);
  __shared__ float sp[4][10];
  int w = threadIdx.x >> 6, ln = threadIdx.x & 63;
  if (ln == 0) {
#pragma unroll
    for (int k = 0; k < 10; ++k) sp[w][k] = p[k];
  }
  __syncthreads();
  if (threadIdx.x < 10)
    part[blockIdx.x * 10 + threadIdx.x] =
        sp[0][threadIdx.x] + sp[1][threadIdx.x] + sp[2][threadIdx.x] + sp[3][threadIdx.x];
}

__global__ void k_finish(const float* __restrict__ part, const float* __restrict__ Wdn,
                         const float* __restrict__ bdn, const float* __restrict__ Wv,
                         const float* __restrict__ bv, float* __restrict__ out, int n, int nPart) {
  __shared__ float m[10];
  int t = threadIdx.x;
  if (t < 10) {
    float s = 0.f;
    for (int b = 0; b < nPart; ++b) s += part[b * 10 + t];
    m[t] = s / (float)n;
  }
  __syncthreads();
  if (t == 0) {
    float pn = bdn[0], vv = bv[0];
    for (int k = 0; k < 10; ++k) {
      pn = fmaf(m[k], Wdn[k], pn);
      vv = fmaf(m[k], Wv[k], vv);
    }
    out[n] = pn;
    out[n + 1] = vv;
  }
}

extern "C" void kernel_launch(void* const* d_in, const int* in_sizes, int n_in,
                              void* d_out, int out_size, void* d_ws, size_t ws_size,
                              hipStream_t stream) {
  const float* x  = (const float*)d_in[0];
  const int* ei   = (const int*)d_in[1];
  const float* W1 = (const float*)d_in[2];
  const float* b1 = (const float*)d_in[3];
  const float* W2 = (const float*)d_in[4];
  const float* b2 = (const float*)d_in[5];
  const float* Wp = (const float*)d_in[6];
  const float* bp = (const float*)d_in[7];
  const float* W3 = (const float*)d_in[8];
  const float* b3 = (const float*)d_in[9];
  const float* Wo = (const float*)d_in[10];
  const float* bo = (const float*)d_in[11];
  const float* Wdn = (const float*)d_in[12];
  const float* bdn = (const float*)d_in[13];
  const float* Wv = (const float*)d_in[14];
  const float* bv = (const float*)d_in[15];

  int N = in_sizes[0] / 128;
  int E = in_sizes[1] / 2;
  const int* row = ei;
  const int* colv = ei + E;
  float* out = (float*)d_out;
  int nbuck = (N + NPB - 1) >> BSH;            // <= 512
  int bb = (E + BIN_CHUNK - 1) / BIN_CHUNK;
  size_t M = (size_t)nbuck * bb;

  char* ws = (char*)d_ws;
  size_t off = 0;
  auto alloc = [&](size_t b) -> void* {
    void* p = ws + off;
    off += (b + 255) & ~(size_t)255;
    return p;
  };
  int* csr_r = (int*)alloc((size_t)(E + N) * 4);
  int* csr_c = (int*)alloc((size_t)(E + N) * 4);
  int* rp_r = (int*)alloc((size_t)(N + 1) * 4);
  int* rp_c = (int*)alloc((size_t)(N + 1) * 4);
  float* dinv_r = (float*)alloc((size_t)N * 4);
  float* dinv_c = (float*)alloc((size_t)N * 4);
  int* hist = (int*)alloc((M + 1) * 4);
  int* bsum = (int*)alloc(4096);
  // union region: bin (build phase) overlaps t_a/t_b/t5/part (compute phase)
  size_t binB = (size_t)E * 4;
  size_t tB = (size_t)N * TS * 2 * 2 + (size_t)N * 4 + 128 * 10 * 4 + 1024;
  char* region = (char*)alloc(binB > tB ? binB : tB);
  int* bin = (int*)region;
  __half* t_a = (__half*)region;
  __half* t_b = (__half*)(region + (size_t)N * TS * 2);
  float* t5 = (float*)(region + (size_t)N * TS * 2 * 2);
  float* part = (float*)(region + (size_t)N * TS * 2 * 2 + (size_t)N * 4);
  if (off > ws_size) {
    fprintf(stderr, "WS too small: need %zu have %zu\n", off, ws_size);
    return;
  }

  int sb2 = (int)((M + 2047) / 2048);
  int ab = (int)(((size_t)N * 16 + 255) / 256);

  // build row-CSR (dst=row, src=col)
  k_histpb<<<bb, 256, 0, stream>>>(row, hist, E, bb, nbuck);
  k_scanA<<<sb2, 256, 0, stream>>>(hist, hist, bsum, (int)M);
  k_scanB<<<1, 1024, 0, stream>>>(bsum, sb2);
  k_scanC<<<sb2, 256, 0, stream>>>(hist, bsum, (int)M, E);
  k_binR<<<bb, 256, 0, stream>>>(row, colv, hist, bin, E, bb, nbuck);
  k_buildcsr<<<nbuck, 512, 0, stream>>>(bin, hist, rp_r, csr_r, dinv_r, N, E, bb);
  // build col-CSR (dst=col, src=row)
  k_histpb<<<bb, 256, 0, stream>>>(colv, hist, E, bb, nbuck);
  k_scanA<<<sb2, 256, 0, stream>>>(hist, hist, bsum, (int)M);
  k_scanB<<<1, 1024, 0, stream>>>(bsum, sb2);
  k_scanC<<<sb2, 256, 0, stream>>>(hist, bsum, (int)M, E);
  k_binR<<<bb, 256, 0, stream>>>(colv, row, hist, bin, E, bb, nbuck);
  k_buildcsr<<<nbuck, 512, 0, stream>>>(bin, hist, rp_c, csr_c, dinv_c, N, E, bb);

  // network (hidden rows fp16, pre-scaled by the NEXT consumer's dinv)
  k_xw<<<2048, 256, 0, stream>>>(x, W1, dinv_r, t_a, N);
  k_agg10<false><<<ab, 256, 0, stream>>>(t_a, t_b, csr_r, rp_r, dinv_r, dinv_r, nullptr, b1, N);
  k_agg10<true><<<ab, 256, 0, stream>>>(t_b, t_a, csr_r, rp_r, dinv_r, dinv_c, W2, b2, N);
  k_agg10<true><<<ab, 256, 0, stream>>>(t_a, t_b, csr_c, rp_c, dinv_c, dinv_r, Wp, bp, N);
  k_agg10<true><<<ab, 256, 0, stream>>>(t_b, t_a, csr_r, rp_r, dinv_r, dinv_r, W3, b3, N);
  k_t5mean<<<128, 256, 0, stream>>>(t_a, Wo, dinv_r, t5, part, N);
  k_agg1<<<ab, 256, 0, stream>>>(t5, out, csr_r, rp_r, dinv_r, bo, N);
  k_finish<<<1, 64, 0, stream>>>(part, Wdn, bdn, Wv, bv, out, N, 128);
}